// Round 1
// baseline (1118.430 us; speedup 1.0000x reference)
//
#include <hip/hip_runtime.h>
#include <hip/hip_cooperative_groups.h>

namespace cg = cooperative_groups;

#define NUM_E 320000
#define NUM_N 10000
#define PADC 32   // ints of stride per counter: one counter per 128B L2 line

typedef __attribute__((ext_vector_type(8))) short bf16x8;
typedef __attribute__((ext_vector_type(4))) float f32x4;

// RNE fp32 -> bf16
__device__ __forceinline__ short f2bf(float f) {
  unsigned u = __builtin_bit_cast(unsigned, f);
  u += 0x7FFFu + ((u >> 16) & 1u);
  return (short)(u >> 16);
}

// RNE-pack two fp32 -> (bf16(y)<<16)|bf16(x) via v_perm_b32 (same rounding math)
__device__ __forceinline__ unsigned pack2bf(float x, float y) {
  unsigned ux = __builtin_bit_cast(unsigned, x);
  unsigned uy = __builtin_bit_cast(unsigned, y);
  ux += 0x7FFFu + ((ux >> 16) & 1u);
  uy += 0x7FFFu + ((uy >> 16) & 1u);
  // bytes [ux.b2, ux.b3, uy.b2, uy.b3]
  return __builtin_amdgcn_perm(uy, ux, 0x07060302u);
}

// ---- one cooperative kernel: zero+repack -> hist -> scan -> scatter ----
// grid MUST stay <= 1024 blocks (4 blocks/CU co-resident guaranteed:
// LDS ~1KB, VGPR capped by __launch_bounds__(256,4)).
__global__ __launch_bounds__(256, 4) void prep_k(
    const float* __restrict__ W1, const float* __restrict__ W2,
    short* __restrict__ Wp, const int* __restrict__ idx,
    int* cntA /* counters, then reused as 'sorted' */,
    int* __restrict__ fillP, float* __restrict__ inv,
    int* __restrict__ blockSum, int* __restrict__ chunkOff,
    float* __restrict__ out) {
  __shared__ int sc[256];
  cg::grid_group grid = cg::this_grid();
  const int t = threadIdx.x;
  const int b = blockIdx.x;
  const int gtid = b * 256 + t;
  const int gsz = gridDim.x * 256;   // 262144

  // ---- phase 0: zero out (10.24MB), zero padded counters, repack weights ----
  for (int i = gtid; i < 640000; i += gsz)
    reinterpret_cast<float4*>(out)[i] = make_float4(0.f, 0.f, 0.f, 0.f);
  for (int i = gtid; i < NUM_N * PADC; i += gsz) cntA[i] = 0;
  if (gtid < 16384) {
    // W[k][n] fp32 -> MFMA B-fragment bf16
    const float* W = (gtid & 8192) ? W2 : W1;
    int r = gtid & 8191;
    short* dst = Wp + (gtid >> 13) * 65536 + r * 8;
    int j = r >> 9;
    int s = (r >> 6) & 7;
    int lane = r & 63;
    int n = j * 16 + (lane & 15);
    int k0 = s * 32 + (lane >> 4) * 8;
    short tmp[8];
#pragma unroll
    for (int e = 0; e < 8; ++e) tmp[e] = f2bf(W[(k0 + e) * 256 + n]);
#pragma unroll
    for (int e = 0; e < 8; ++e) dst[e] = tmp[e];
  }
  grid.sync();

  // ---- phase 1: histogram into padded counters (32 RMWs/line, was ~1024) ----
  for (int e = gtid; e < NUM_E; e += gsz) atomicAdd(&cntA[idx[e] * PADC], 1);
  grid.sync();

  // ---- phase 2a: 40 blocks x 256 nodes: block-local exclusive scan + inv ----
  if (b < 40) {
    int n = b * 256 + t;
    int c = (n < NUM_N) ? cntA[n * PADC] : 0;
    sc[t] = c;
    __syncthreads();
    for (int off = 1; off < 256; off <<= 1) {
      int v = (t >= off) ? sc[t - off] : 0;
      __syncthreads();
      sc[t] += v;
      __syncthreads();
    }
    if (n < NUM_N) {
      fillP[n * PADC] = sc[t] - c;                       // local exclusive
      inv[n] = (c > 0) ? 1.0f / (float)c : 0.0f;
    }
    if (t == 255) blockSum[b] = sc[255];
  }
  grid.sync();

  // ---- phase 2b: tiny serial scan of 40 chunk totals ----
  if (gtid == 0) {
    int s = 0;
    for (int i = 0; i < 40; ++i) { chunkOff[i] = s; s += blockSum[i]; }
  }
  grid.sync();

  // ---- phase 2c: globalize chunk offsets ----
  if (b < 40) {
    int n = b * 256 + t;
    if (n < NUM_N) fillP[n * PADC] += chunkOff[b];
  }
  grid.sync();

  // ---- phase 3: counting-sort scatter (cntA now reused as 'sorted') ----
  for (int e = gtid; e < NUM_E; e += gsz) {
    int ix = idx[e];
    int pos = atomicAdd(&fillP[ix * PADC], 1);
    cntA[pos] = e;
  }
}

// ---- fused MLP over 64 sorted edges + in-register segmented scatter-mean ----
__global__ __launch_bounds__(256, 4) void fused_mlp_gather(
    const float* __restrict__ X, const int* __restrict__ idx,
    const int* __restrict__ sorted,
    const short* __restrict__ Wp1, const short* __restrict__ Wp2,
    const float* __restrict__ b1, const float* __restrict__ b2,
    const float* __restrict__ inv, float* __restrict__ out) {
  __shared__ __align__(16) short Xl[64][264];   // bf16 X, then Y1 (33792 B)
  __shared__ int idxl[64];
  __shared__ int se[64];
  __shared__ int segLo[64];
  __shared__ int segN[64];
  __shared__ int nsegS;

  const int tid = threadIdx.x;
  const int wave = tid >> 6;
  const int lane = tid & 63;
  const int q = lane >> 4;
  const int m = lane & 15;
  const int row0 = blockIdx.x * 64;

  if (tid < 64) {
    int e = sorted[row0 + tid];
    se[tid] = e;
    idxl[tid] = idx[e];
  }
  __syncthreads();

  // stage gathered X rows fp32 -> bf16 into LDS (v_perm pair packing)
  for (int i = tid; i < 64 * 64; i += 256) {
    int r = i >> 6, c4 = i & 63;
    const float4 v = reinterpret_cast<const float4*>(X + (size_t)se[r] * 256)[c4];
    uint2 p;
    p.x = pack2bf(v.x, v.y);
    p.y = pack2bf(v.z, v.w);
    *reinterpret_cast<uint2*>(&Xl[r][c4 * 4]) = p;
  }
  __syncthreads();

  // segment list (runs in sorted idxl) — wave 0; visible after next barrier
  if (wave == 0) {
    bool flag = (lane == 0) || (idxl[lane] != idxl[lane - 1]);
    unsigned long long mask = __ballot(flag);
    if (lane == 0) nsegS = (int)__popcll(mask);
    if (flag) {
      int sidx = (int)__popcll(mask & ((1ull << lane) - 1ull));
      segLo[sidx] = lane;
      segN[sidx] = idxl[lane];
    }
  }

  // ---- layer 1 ----
  f32x4 acc[4][4];
#pragma unroll
  for (int mi = 0; mi < 4; ++mi)
#pragma unroll
    for (int nj = 0; nj < 4; ++nj) acc[mi][nj] = (f32x4)0.0f;

#pragma unroll
  for (int s = 0; s < 8; ++s) {
    bf16x8 a[4], b[4];
#pragma unroll
    for (int mi = 0; mi < 4; ++mi)
      a[mi] = *reinterpret_cast<const bf16x8*>(&Xl[mi * 16 + m][s * 32 + q * 8]);
#pragma unroll
    for (int nj = 0; nj < 4; ++nj)
      b[nj] = *reinterpret_cast<const bf16x8*>(
          Wp1 + (size_t)(((wave * 4 + nj) * 8 + s) * 64 + lane) * 8);
#pragma unroll
    for (int mi = 0; mi < 4; ++mi)
#pragma unroll
      for (int nj = 0; nj < 4; ++nj)
        acc[mi][nj] = __builtin_amdgcn_mfma_f32_16x16x32_bf16(a[mi], b[nj],
                                                              acc[mi][nj], 0, 0, 0);
  }
  __syncthreads();   // done reading X

  float bias1[4];
#pragma unroll
  for (int nj = 0; nj < 4; ++nj) bias1[nj] = b1[wave * 64 + nj * 16 + m];
#pragma unroll
  for (int mi = 0; mi < 4; ++mi)
#pragma unroll
    for (int nj = 0; nj < 4; ++nj)
#pragma unroll
      for (int r4 = 0; r4 < 4; ++r4) {
        float v = fmaxf(acc[mi][nj][r4] + bias1[nj], 0.0f);
        Xl[mi * 16 + q * 4 + r4][wave * 64 + nj * 16 + m] = f2bf(v);
      }
  __syncthreads();

  // ---- layer 2 ----
#pragma unroll
  for (int mi = 0; mi < 4; ++mi)
#pragma unroll
    for (int nj = 0; nj < 4; ++nj) acc[mi][nj] = (f32x4)0.0f;

#pragma unroll
  for (int s = 0; s < 8; ++s) {
    bf16x8 a[4], b[4];
#pragma unroll
    for (int mi = 0; mi < 4; ++mi)
      a[mi] = *reinterpret_cast<const bf16x8*>(&Xl[mi * 16 + m][s * 32 + q * 8]);
#pragma unroll
    for (int nj = 0; nj < 4; ++nj)
      b[nj] = *reinterpret_cast<const bf16x8*>(
          Wp2 + (size_t)(((wave * 4 + nj) * 8 + s) * 64 + lane) * 8);
#pragma unroll
    for (int mi = 0; mi < 4; ++mi)
#pragma unroll
      for (int nj = 0; nj < 4; ++nj)
        acc[mi][nj] = __builtin_amdgcn_mfma_f32_16x16x32_bf16(a[mi], b[nj],
                                                              acc[mi][nj], 0, 0, 0);
  }

  // bias2 + relu in-register
  float bias2[4];
#pragma unroll
  for (int nj = 0; nj < 4; ++nj) bias2[nj] = b2[wave * 64 + nj * 16 + m];
#pragma unroll
  for (int mi = 0; mi < 4; ++mi)
#pragma unroll
    for (int nj = 0; nj < 4; ++nj)
#pragma unroll
      for (int r4 = 0; r4 < 4; ++r4)
        acc[mi][nj][r4] = fmaxf(acc[mi][nj][r4] + bias2[nj], 0.0f);

  // ---- in-register segmented reduce + scatter ----
  // value acc[mi][nj][r4] is Y2[row=mi*16+q*4+r4][col=wave*64+nj*16+m]
  int nseg = nsegS;
  for (int s = 0; s < nseg; ++s) {
    int lo = segLo[s];
    int hi = (s + 1 < nseg) ? segLo[s + 1] : 64;
    int node = segN[s];
    float sum[4] = {0.0f, 0.0f, 0.0f, 0.0f};
#pragma unroll
    for (int mi = 0; mi < 4; ++mi)
#pragma unroll
      for (int r4 = 0; r4 < 4; ++r4) {
        int row = mi * 16 + q * 4 + r4;
        float msk = (row >= lo && row < hi) ? 1.0f : 0.0f;
#pragma unroll
        for (int nj = 0; nj < 4; ++nj) sum[nj] = fmaf(msk, acc[mi][nj][r4], sum[nj]);
      }
    float scale = inv[node];
#pragma unroll
    for (int nj = 0; nj < 4; ++nj) {
      float v = sum[nj];
      v += __shfl_xor(v, 16, 64);
      v += __shfl_xor(v, 32, 64);
      if (q == 0 && v != 0.0f)
        atomicAdd(&out[(size_t)node * 256 + wave * 64 + nj * 16 + m], v * scale);
    }
  }
}

extern "C" void kernel_launch(void* const* d_in, const int* in_sizes, int n_in,
                              void* d_out, int out_size, void* d_ws, size_t ws_size,
                              hipStream_t stream) {
  const float* X   = (const float*)d_in[0];
  const int*   idx = (const int*)d_in[1];
  const float* W1  = (const float*)d_in[3];
  const float* b1  = (const float*)d_in[4];
  const float* W2  = (const float*)d_in[5];
  const float* b2  = (const float*)d_in[6];
  float* out = (float*)d_out;

  char* ws = (char*)d_ws;
  short* Wp       = (short*)(ws);                 // 262,144 B
  int*   cntA     = (int*)(ws + 262144);          // 1,280,000 B (counters -> sorted)
  int*   fillP    = (int*)(ws + 1542144);         // 1,280,000 B
  float* inv      = (float*)(ws + 2822144);       //    40,000 B
  int*   blockSum = (int*)(ws + 2862144);         //       256 B
  int*   chunkOff = (int*)(ws + 2862400);         //       256 B
  int*   sorted   = cntA;                         // alias: counters dead by phase 3

  void* args[] = {(void*)&W1, (void*)&W2, (void*)&Wp, (void*)&idx,
                  (void*)&cntA, (void*)&fillP, (void*)&inv,
                  (void*)&blockSum, (void*)&chunkOff, (void*)&out};
  hipLaunchCooperativeKernel((void*)prep_k, dim3(1024), dim3(256), args, 0, stream);

  fused_mlp_gather<<<NUM_E / 64, 256, 0, stream>>>(
      X, idx, sorted, Wp, Wp + 65536, b1, b2, inv, out);
}

// Round 3
// 588.092 us; speedup vs baseline: 1.9018x; 1.9018x over previous
//
#include <hip/hip_runtime.h>

#define NUM_E 320000
#define NUM_N 10000
#define PADC 32   // ints of stride per counter: one counter per 128B L2 line

typedef __attribute__((ext_vector_type(8))) short bf16x8;
typedef __attribute__((ext_vector_type(4))) float f32x4;

// RNE fp32 -> bf16
__device__ __forceinline__ short f2bf(float f) {
  unsigned u = __builtin_bit_cast(unsigned, f);
  u += 0x7FFFu + ((u >> 16) & 1u);
  return (short)(u >> 16);
}

// RNE-pack two fp32 -> (bf16(y)<<16)|bf16(x) via v_perm_b32 (same rounding math)
__device__ __forceinline__ unsigned pack2bf(float x, float y) {
  unsigned ux = __builtin_bit_cast(unsigned, x);
  unsigned uy = __builtin_bit_cast(unsigned, y);
  ux += 0x7FFFu + ((ux >> 16) & 1u);
  uy += 0x7FFFu + ((uy >> 16) & 1u);
  return __builtin_amdgcn_perm(uy, ux, 0x07060302u);
}

// ---- k0: zero out (10.24MB) + zero padded counters (1.28MB) + repack weights ----
__global__ __launch_bounds__(256) void zero_repack_k(
    const float* __restrict__ W1, const float* __restrict__ W2,
    short* __restrict__ Wp, int* __restrict__ cntA, float* __restrict__ out) {
  const int gtid = blockIdx.x * 256 + threadIdx.x;
  const int gsz = gridDim.x * 256;
  for (int i = gtid; i < 640000; i += gsz)
    reinterpret_cast<float4*>(out)[i] = make_float4(0.f, 0.f, 0.f, 0.f);
  for (int i = gtid; i < NUM_N * PADC / 4; i += gsz)
    reinterpret_cast<int4*>(cntA)[i] = make_int4(0, 0, 0, 0);
  if (gtid < 16384) {
    // W[k][n] fp32 -> MFMA B-fragment bf16
    const float* W = (gtid & 8192) ? W2 : W1;
    int r = gtid & 8191;
    short* dst = Wp + (gtid >> 13) * 65536 + r * 8;
    int j = r >> 9;
    int s = (r >> 6) & 7;
    int lane = r & 63;
    int n = j * 16 + (lane & 15);
    int k0 = s * 32 + (lane >> 4) * 8;
    short tmp[8];
#pragma unroll
    for (int e = 0; e < 8; ++e) tmp[e] = f2bf(W[(k0 + e) * 256 + n]);
#pragma unroll
    for (int e = 0; e < 8; ++e) dst[e] = tmp[e];
  }
}

// ---- k1: histogram into line-padded counters ----
__global__ __launch_bounds__(256) void hist_k(const int* __restrict__ idx,
                                              int* __restrict__ cntA) {
  int e = blockIdx.x * 256 + threadIdx.x;
  if (e < NUM_E) atomicAdd(&cntA[idx[e] * PADC], 1);
}

// ---- k2: single-block exclusive prefix sum over padded counters -> fillP, inv ----
__global__ __launch_bounds__(256) void scan_k(const int* __restrict__ cntA,
                                              int* __restrict__ fillP,
                                              float* __restrict__ inv) {
  __shared__ int part[256];
  int t = threadIdx.x;
  int base = t * 40;
  int local[40];
  int s = 0;
#pragma unroll
  for (int i = 0; i < 40; ++i) {
    int n = base + i;
    int c = (n < NUM_N) ? cntA[n * PADC] : 0;
    local[i] = s;
    s += c;
  }
  part[t] = s;
  __syncthreads();
  for (int off = 1; off < 256; off <<= 1) {
    int tmp = 0;
    if (t >= off) tmp = part[t - off];
    __syncthreads();
    if (t >= off) part[t] += tmp;
    __syncthreads();
  }
  int ebase = (t == 0) ? 0 : part[t - 1];
#pragma unroll
  for (int i = 0; i < 40; ++i) {
    int n = base + i;
    if (n < NUM_N) {
      fillP[n * PADC] = ebase + local[i];
      int c = cntA[n * PADC];
      inv[n] = (c > 0) ? 1.0f / (float)c : 0.0f;
    }
  }
}

// ---- k3: counting-sort scatter via line-padded fill cursors ----
__global__ __launch_bounds__(256) void scatter_k(const int* __restrict__ idx,
                                                 int* __restrict__ fillP,
                                                 int* __restrict__ sorted) {
  int e = blockIdx.x * 256 + threadIdx.x;
  if (e < NUM_E) {
    int ix = idx[e];
    int pos = atomicAdd(&fillP[ix * PADC], 1);
    sorted[pos] = e;
  }
}

// ---- fused MLP over 64 sorted edges + in-register segmented scatter-mean ----
__global__ __launch_bounds__(256, 4) void fused_mlp_gather(
    const float* __restrict__ X, const int* __restrict__ idx,
    const int* __restrict__ sorted,
    const short* __restrict__ Wp1, const short* __restrict__ Wp2,
    const float* __restrict__ b1, const float* __restrict__ b2,
    const float* __restrict__ inv, float* __restrict__ out) {
  __shared__ __align__(16) short Xl[64][264];   // bf16 X, then Y1 (33792 B)
  __shared__ int idxl[64];
  __shared__ int se[64];
  __shared__ int segLo[64];
  __shared__ int segN[64];
  __shared__ int nsegS;

  const int tid = threadIdx.x;
  const int wave = tid >> 6;
  const int lane = tid & 63;
  const int q = lane >> 4;
  const int m = lane & 15;
  const int row0 = blockIdx.x * 64;

  if (tid < 64) {
    int e = sorted[row0 + tid];
    se[tid] = e;
    idxl[tid] = idx[e];
  }
  __syncthreads();

  // stage gathered X rows fp32 -> bf16 into LDS (v_perm pair packing)
  for (int i = tid; i < 64 * 64; i += 256) {
    int r = i >> 6, c4 = i & 63;
    const float4 v = reinterpret_cast<const float4*>(X + (size_t)se[r] * 256)[c4];
    uint2 p;
    p.x = pack2bf(v.x, v.y);
    p.y = pack2bf(v.z, v.w);
    *reinterpret_cast<uint2*>(&Xl[r][c4 * 4]) = p;
  }
  __syncthreads();

  // segment list (runs in sorted idxl) — wave 0; visible after next barrier
  if (wave == 0) {
    bool flag = (lane == 0) || (idxl[lane] != idxl[lane - 1]);
    unsigned long long mask = __ballot(flag);
    if (lane == 0) nsegS = (int)__popcll(mask);
    if (flag) {
      int sidx = (int)__popcll(mask & ((1ull << lane) - 1ull));
      segLo[sidx] = lane;
      segN[sidx] = idxl[lane];
    }
  }

  // ---- layer 1 ----
  f32x4 acc[4][4];
#pragma unroll
  for (int mi = 0; mi < 4; ++mi)
#pragma unroll
    for (int nj = 0; nj < 4; ++nj) acc[mi][nj] = (f32x4)0.0f;

#pragma unroll
  for (int s = 0; s < 8; ++s) {
    bf16x8 a[4], b[4];
#pragma unroll
    for (int mi = 0; mi < 4; ++mi)
      a[mi] = *reinterpret_cast<const bf16x8*>(&Xl[mi * 16 + m][s * 32 + q * 8]);
#pragma unroll
    for (int nj = 0; nj < 4; ++nj)
      b[nj] = *reinterpret_cast<const bf16x8*>(
          Wp1 + (size_t)(((wave * 4 + nj) * 8 + s) * 64 + lane) * 8);
#pragma unroll
    for (int mi = 0; mi < 4; ++mi)
#pragma unroll
      for (int nj = 0; nj < 4; ++nj)
        acc[mi][nj] = __builtin_amdgcn_mfma_f32_16x16x32_bf16(a[mi], b[nj],
                                                              acc[mi][nj], 0, 0, 0);
  }
  __syncthreads();   // done reading X

  float bias1[4];
#pragma unroll
  for (int nj = 0; nj < 4; ++nj) bias1[nj] = b1[wave * 64 + nj * 16 + m];
#pragma unroll
  for (int mi = 0; mi < 4; ++mi)
#pragma unroll
    for (int nj = 0; nj < 4; ++nj)
#pragma unroll
      for (int r4 = 0; r4 < 4; ++r4) {
        float v = fmaxf(acc[mi][nj][r4] + bias1[nj], 0.0f);
        Xl[mi * 16 + q * 4 + r4][wave * 64 + nj * 16 + m] = f2bf(v);
      }
  __syncthreads();

  // ---- layer 2 ----
#pragma unroll
  for (int mi = 0; mi < 4; ++mi)
#pragma unroll
    for (int nj = 0; nj < 4; ++nj) acc[mi][nj] = (f32x4)0.0f;

#pragma unroll
  for (int s = 0; s < 8; ++s) {
    bf16x8 a[4], b[4];
#pragma unroll
    for (int mi = 0; mi < 4; ++mi)
      a[mi] = *reinterpret_cast<const bf16x8*>(&Xl[mi * 16 + m][s * 32 + q * 8]);
#pragma unroll
    for (int nj = 0; nj < 4; ++nj)
      b[nj] = *reinterpret_cast<const bf16x8*>(
          Wp2 + (size_t)(((wave * 4 + nj) * 8 + s) * 64 + lane) * 8);
#pragma unroll
    for (int mi = 0; mi < 4; ++mi)
#pragma unroll
      for (int nj = 0; nj < 4; ++nj)
        acc[mi][nj] = __builtin_amdgcn_mfma_f32_16x16x32_bf16(a[mi], b[nj],
                                                              acc[mi][nj], 0, 0, 0);
  }

  // bias2 + relu in-register
  float bias2[4];
#pragma unroll
  for (int nj = 0; nj < 4; ++nj) bias2[nj] = b2[wave * 64 + nj * 16 + m];
#pragma unroll
  for (int mi = 0; mi < 4; ++mi)
#pragma unroll
    for (int nj = 0; nj < 4; ++nj)
#pragma unroll
      for (int r4 = 0; r4 < 4; ++r4)
        acc[mi][nj][r4] = fmaxf(acc[mi][nj][r4] + bias2[nj], 0.0f);

  // ---- in-register segmented reduce + scatter ----
  // value acc[mi][nj][r4] is Y2[row=mi*16+q*4+r4][col=wave*64+nj*16+m]
  int nseg = nsegS;
  for (int s = 0; s < nseg; ++s) {
    int lo = segLo[s];
    int hi = (s + 1 < nseg) ? segLo[s + 1] : 64;
    int node = segN[s];
    float sum[4] = {0.0f, 0.0f, 0.0f, 0.0f};
#pragma unroll
    for (int mi = 0; mi < 4; ++mi)
#pragma unroll
      for (int r4 = 0; r4 < 4; ++r4) {
        int row = mi * 16 + q * 4 + r4;
        float msk = (row >= lo && row < hi) ? 1.0f : 0.0f;
#pragma unroll
        for (int nj = 0; nj < 4; ++nj) sum[nj] = fmaf(msk, acc[mi][nj][r4], sum[nj]);
      }
    float scale = inv[node];
#pragma unroll
    for (int nj = 0; nj < 4; ++nj) {
      float v = sum[nj];
      v += __shfl_xor(v, 16, 64);
      v += __shfl_xor(v, 32, 64);
      if (q == 0 && v != 0.0f)
        atomicAdd(&out[(size_t)node * 256 + wave * 64 + nj * 16 + m], v * scale);
    }
  }
}

extern "C" void kernel_launch(void* const* d_in, const int* in_sizes, int n_in,
                              void* d_out, int out_size, void* d_ws, size_t ws_size,
                              hipStream_t stream) {
  const float* X   = (const float*)d_in[0];
  const int*   idx = (const int*)d_in[1];
  const float* W1  = (const float*)d_in[3];
  const float* b1  = (const float*)d_in[4];
  const float* W2  = (const float*)d_in[5];
  const float* b2  = (const float*)d_in[6];
  float* out = (float*)d_out;

  char* ws = (char*)d_ws;
  short* Wp    = (short*)(ws);                 // 262,144 B
  int*   cntA  = (int*)(ws + 262144);          // 1,280,000 B (counters; reused as sorted)
  int*   fillP = (int*)(ws + 1542144);         // 1,280,000 B
  float* inv   = (float*)(ws + 2822144);       //    40,000 B
  int*   sorted = cntA;                        // alias: counters dead after scan_k

  zero_repack_k<<<2048, 256, 0, stream>>>(W1, W2, Wp, cntA, out);
  hist_k<<<(NUM_E + 255) / 256, 256, 0, stream>>>(idx, cntA);
  scan_k<<<1, 256, 0, stream>>>(cntA, fillP, inv);
  scatter_k<<<(NUM_E + 255) / 256, 256, 0, stream>>>(idx, fillP, sorted);
  fused_mlp_gather<<<NUM_E / 64, 256, 0, stream>>>(
      X, idx, sorted, Wp, Wp + 65536, b1, b2, inv, out);
}

// Round 4
// 545.342 us; speedup vs baseline: 2.0509x; 1.0784x over previous
//
#include <hip/hip_runtime.h>

#define NUM_E 320000
#define NUM_N 10000
#define PADC 32   // ints of stride per counter: one counter per 128B L2 line

typedef __attribute__((ext_vector_type(8))) short bf16x8;
typedef __attribute__((ext_vector_type(4))) float f32x4;

// RNE fp32 -> bf16
__device__ __forceinline__ short f2bf(float f) {
  unsigned u = __builtin_bit_cast(unsigned, f);
  u += 0x7FFFu + ((u >> 16) & 1u);
  return (short)(u >> 16);
}

// RNE-pack two fp32 -> (bf16(y)<<16)|bf16(x) via v_perm_b32 (same rounding math)
__device__ __forceinline__ unsigned pack2bf(float x, float y) {
  unsigned ux = __builtin_bit_cast(unsigned, x);
  unsigned uy = __builtin_bit_cast(unsigned, y);
  ux += 0x7FFFu + ((ux >> 16) & 1u);
  uy += 0x7FFFu + ((uy >> 16) & 1u);
  return __builtin_amdgcn_perm(uy, ux, 0x07060302u);
}

// ---- k0: zero out (10.24MB) + zero padded counters + cursor + repack weights ----
__global__ __launch_bounds__(256) void zero_repack_k(
    const float* __restrict__ W1, const float* __restrict__ W2,
    short* __restrict__ Wp, int* __restrict__ cntA, int* __restrict__ cursor,
    float* __restrict__ out) {
  const int gtid = blockIdx.x * 256 + threadIdx.x;
  const int gsz = gridDim.x * 256;
  if (gtid == 0) *cursor = 0;
  for (int i = gtid; i < 640000; i += gsz)
    reinterpret_cast<float4*>(out)[i] = make_float4(0.f, 0.f, 0.f, 0.f);
  for (int i = gtid; i < NUM_N * PADC / 4; i += gsz)
    reinterpret_cast<int4*>(cntA)[i] = make_int4(0, 0, 0, 0);
  if (gtid < 16384) {
    // W[k][n] fp32 -> MFMA B-fragment bf16
    const float* W = (gtid & 8192) ? W2 : W1;
    int r = gtid & 8191;
    short* dst = Wp + (gtid >> 13) * 65536 + r * 8;
    int j = r >> 9;
    int s = (r >> 6) & 7;
    int lane = r & 63;
    int n = j * 16 + (lane & 15);
    int k0 = s * 32 + (lane >> 4) * 8;
    short tmp[8];
#pragma unroll
    for (int e = 0; e < 8; ++e) tmp[e] = f2bf(W[(k0 + e) * 256 + n]);
#pragma unroll
    for (int e = 0; e < 8; ++e) dst[e] = tmp[e];
  }
}

// ---- k1: histogram into line-padded counters ----
__global__ __launch_bounds__(256) void hist_k(const int* __restrict__ idx,
                                              int* __restrict__ cntA) {
  int e = blockIdx.x * 256 + threadIdx.x;
  if (e < NUM_E) atomicAdd(&cntA[idx[e] * PADC], 1);
}

// ---- k2: parallel segment-offset allocation (order-free, no global scan) ----
// Segments only need to be contiguous; node order in 'sorted' is irrelevant.
__global__ __launch_bounds__(256) void alloc_k(const int* __restrict__ cntA,
                                               int* __restrict__ fillP,
                                               float* __restrict__ inv,
                                               int* __restrict__ cursor) {
  int n = blockIdx.x * 256 + threadIdx.x;
  int lane = threadIdx.x & 63;
  int c = (n < NUM_N) ? cntA[n * PADC] : 0;
  // wave-inclusive prefix sum of c
  int pre = c;
#pragma unroll
  for (int off = 1; off < 64; off <<= 1) {
    int v = __shfl_up(pre, off, 64);
    if (lane >= off) pre += v;
  }
  int tot = __shfl(pre, 63, 64);
  int base = 0;
  if (lane == 63) base = atomicAdd(cursor, tot);
  base = __shfl(base, 63, 64);
  if (n < NUM_N) {
    fillP[n * PADC] = base + pre - c;   // exclusive within wave + wave base
    inv[n] = (c > 0) ? 1.0f / (float)c : 0.0f;
  }
}

// ---- k3: counting-sort scatter via line-padded fill cursors ----
__global__ __launch_bounds__(256) void scatter_k(const int* __restrict__ idx,
                                                 int* __restrict__ fillP,
                                                 int* __restrict__ sorted) {
  int e = blockIdx.x * 256 + threadIdx.x;
  if (e < NUM_E) {
    int ix = idx[e];
    int pos = atomicAdd(&fillP[ix * PADC], 1);
    sorted[pos] = e;
  }
}

// ---- fused MLP over 64 sorted edges + in-register segmented scatter-mean ----
// launch_bounds(256,3): VGPR cap ~170 so the 16 gather loads + acc[4][4] AGPRs
// can coexist -> ~16 outstanding b128 gathers per wave (MLP, not BW, is the
// bottleneck at 64 VGPR).
__global__ __launch_bounds__(256, 3) void fused_mlp_gather(
    const float* __restrict__ X, const int* __restrict__ idx,
    const int* __restrict__ sorted,
    const short* __restrict__ Wp1, const short* __restrict__ Wp2,
    const float* __restrict__ b1, const float* __restrict__ b2,
    const float* __restrict__ inv, float* __restrict__ out) {
  __shared__ __align__(16) short Xl[64][264];   // bf16 X, then Y1 (33792 B)
  __shared__ int idxl[64];
  __shared__ int se[64];
  __shared__ int segLo[64];
  __shared__ int segN[64];
  __shared__ int nsegS;

  const int tid = threadIdx.x;
  const int wave = tid >> 6;
  const int lane = tid & 63;
  const int q = lane >> 4;
  const int m = lane & 15;
  const int row0 = blockIdx.x * 64;

  if (tid < 64) {
    int e = sorted[row0 + tid];
    se[tid] = e;
    idxl[tid] = idx[e];
  }
  __syncthreads();

  // stage gathered X rows: issue ALL 16 loads first (max memory-level
  // parallelism), then pack fp32->bf16 into LDS.
  float4 vbuf[16];
#pragma unroll
  for (int k = 0; k < 16; ++k) {
    int i = tid + k * 256;
    int r = i >> 6, c4 = i & 63;
    vbuf[k] = reinterpret_cast<const float4*>(X + (size_t)se[r] * 256)[c4];
  }
#pragma unroll
  for (int k = 0; k < 16; ++k) {
    int i = tid + k * 256;
    int r = i >> 6, c4 = i & 63;
    uint2 p;
    p.x = pack2bf(vbuf[k].x, vbuf[k].y);
    p.y = pack2bf(vbuf[k].z, vbuf[k].w);
    *reinterpret_cast<uint2*>(&Xl[r][c4 * 4]) = p;
  }
  __syncthreads();

  // segment list (runs in sorted idxl) — wave 0; visible after next barrier
  if (wave == 0) {
    bool flag = (lane == 0) || (idxl[lane] != idxl[lane - 1]);
    unsigned long long mask = __ballot(flag);
    if (lane == 0) nsegS = (int)__popcll(mask);
    if (flag) {
      int sidx = (int)__popcll(mask & ((1ull << lane) - 1ull));
      segLo[sidx] = lane;
      segN[sidx] = idxl[lane];
    }
  }

  // ---- layer 1 ----
  f32x4 acc[4][4];
#pragma unroll
  for (int mi = 0; mi < 4; ++mi)
#pragma unroll
    for (int nj = 0; nj < 4; ++nj) acc[mi][nj] = (f32x4)0.0f;

#pragma unroll
  for (int s = 0; s < 8; ++s) {
    bf16x8 a[4], b[4];
#pragma unroll
    for (int mi = 0; mi < 4; ++mi)
      a[mi] = *reinterpret_cast<const bf16x8*>(&Xl[mi * 16 + m][s * 32 + q * 8]);
#pragma unroll
    for (int nj = 0; nj < 4; ++nj)
      b[nj] = *reinterpret_cast<const bf16x8*>(
          Wp1 + (size_t)(((wave * 4 + nj) * 8 + s) * 64 + lane) * 8);
    __builtin_amdgcn_s_setprio(1);
#pragma unroll
    for (int mi = 0; mi < 4; ++mi)
#pragma unroll
      for (int nj = 0; nj < 4; ++nj)
        acc[mi][nj] = __builtin_amdgcn_mfma_f32_16x16x32_bf16(a[mi], b[nj],
                                                              acc[mi][nj], 0, 0, 0);
    __builtin_amdgcn_s_setprio(0);
  }
  __syncthreads();   // done reading X

  float bias1[4];
#pragma unroll
  for (int nj = 0; nj < 4; ++nj) bias1[nj] = b1[wave * 64 + nj * 16 + m];
#pragma unroll
  for (int mi = 0; mi < 4; ++mi)
#pragma unroll
    for (int nj = 0; nj < 4; ++nj)
#pragma unroll
      for (int r4 = 0; r4 < 4; ++r4) {
        float v = fmaxf(acc[mi][nj][r4] + bias1[nj], 0.0f);
        Xl[mi * 16 + q * 4 + r4][wave * 64 + nj * 16 + m] = f2bf(v);
      }
  __syncthreads();

  // ---- layer 2 ----
#pragma unroll
  for (int mi = 0; mi < 4; ++mi)
#pragma unroll
    for (int nj = 0; nj < 4; ++nj) acc[mi][nj] = (f32x4)0.0f;

#pragma unroll
  for (int s = 0; s < 8; ++s) {
    bf16x8 a[4], b[4];
#pragma unroll
    for (int mi = 0; mi < 4; ++mi)
      a[mi] = *reinterpret_cast<const bf16x8*>(&Xl[mi * 16 + m][s * 32 + q * 8]);
#pragma unroll
    for (int nj = 0; nj < 4; ++nj)
      b[nj] = *reinterpret_cast<const bf16x8*>(
          Wp2 + (size_t)(((wave * 4 + nj) * 8 + s) * 64 + lane) * 8);
    __builtin_amdgcn_s_setprio(1);
#pragma unroll
    for (int mi = 0; mi < 4; ++mi)
#pragma unroll
      for (int nj = 0; nj < 4; ++nj)
        acc[mi][nj] = __builtin_amdgcn_mfma_f32_16x16x32_bf16(a[mi], b[nj],
                                                              acc[mi][nj], 0, 0, 0);
    __builtin_amdgcn_s_setprio(0);
  }

  // bias2 + relu in-register
  float bias2[4];
#pragma unroll
  for (int nj = 0; nj < 4; ++nj) bias2[nj] = b2[wave * 64 + nj * 16 + m];
#pragma unroll
  for (int mi = 0; mi < 4; ++mi)
#pragma unroll
    for (int nj = 0; nj < 4; ++nj)
#pragma unroll
      for (int r4 = 0; r4 < 4; ++r4)
        acc[mi][nj][r4] = fmaxf(acc[mi][nj][r4] + bias2[nj], 0.0f);

  // ---- in-register segmented reduce + scatter ----
  // value acc[mi][nj][r4] is Y2[row=mi*16+q*4+r4][col=wave*64+nj*16+m]
  int nseg = nsegS;
  for (int s = 0; s < nseg; ++s) {
    int lo = segLo[s];
    int hi = (s + 1 < nseg) ? segLo[s + 1] : 64;
    int node = segN[s];
    float sum[4] = {0.0f, 0.0f, 0.0f, 0.0f};
#pragma unroll
    for (int mi = 0; mi < 4; ++mi)
#pragma unroll
      for (int r4 = 0; r4 < 4; ++r4) {
        int row = mi * 16 + q * 4 + r4;
        float msk = (row >= lo && row < hi) ? 1.0f : 0.0f;
#pragma unroll
        for (int nj = 0; nj < 4; ++nj) sum[nj] = fmaf(msk, acc[mi][nj][r4], sum[nj]);
      }
    float scale = inv[node];
#pragma unroll
    for (int nj = 0; nj < 4; ++nj) {
      float v = sum[nj];
      v += __shfl_xor(v, 16, 64);
      v += __shfl_xor(v, 32, 64);
      if (q == 0 && v != 0.0f)
        atomicAdd(&out[(size_t)node * 256 + wave * 64 + nj * 16 + m], v * scale);
    }
  }
}

extern "C" void kernel_launch(void* const* d_in, const int* in_sizes, int n_in,
                              void* d_out, int out_size, void* d_ws, size_t ws_size,
                              hipStream_t stream) {
  const float* X   = (const float*)d_in[0];
  const int*   idx = (const int*)d_in[1];
  const float* W1  = (const float*)d_in[3];
  const float* b1  = (const float*)d_in[4];
  const float* W2  = (const float*)d_in[5];
  const float* b2  = (const float*)d_in[6];
  float* out = (float*)d_out;

  char* ws = (char*)d_ws;
  short* Wp     = (short*)(ws);                 // 262,144 B
  int*   cntA   = (int*)(ws + 262144);          // 1,280,000 B (counters; reused as sorted)
  int*   fillP  = (int*)(ws + 1542144);         // 1,280,000 B
  float* inv    = (float*)(ws + 2822144);       //    40,960 B
  int*   cursor = (int*)(ws + 2863104);         //         4 B
  int*   sorted = cntA;                         // alias: counters dead after alloc_k

  zero_repack_k<<<2048, 256, 0, stream>>>(W1, W2, Wp, cntA, cursor, out);
  hist_k<<<(NUM_E + 255) / 256, 256, 0, stream>>>(idx, cntA);
  alloc_k<<<40, 256, 0, stream>>>(cntA, fillP, inv, cursor);
  scatter_k<<<(NUM_E + 255) / 256, 256, 0, stream>>>(idx, fillP, sorted);
  fused_mlp_gather<<<NUM_E / 64, 256, 0, stream>>>(
      X, idx, sorted, Wp, Wp + 65536, b1, b2, inv, out);
}